// Round 4
// baseline (172.057 us; speedup 1.0000x reference)
//
#include <hip/hip_runtime.h>

// MoE_52037823758984: out[i] = x[i] @ W_{route[i]}^T + b_{route[i]}
// N = 2,097,152 tokens, D = 10, all f32 (route int32).
//
// R4 = R3 with the nontemporal-store type fixed (native ext_vector float4).
//  - Persistent blocks: 1024 blocks (4/CU, co-resident) x 4 chunks each.
//  - Register double-buffer: chunk c+1's 6 global loads issued before chunk
//    c's LDS/compute/store -> loads always in flight (partial vmcnt waits).
//  - Wave-private LDS reshuffle, conflict-free (measured 0 in R2).
//  - Output stores nontemporal (streaming, no reuse).

#define BLOCK 256
#define D 10
#define WAVE_ROWS 128              // rows per wave per chunk
#define F4_PER_WAVE 320            // 128*10/4
#define BLK_ROWS (4 * WAVE_ROWS)   // 512 rows per block-chunk (4 waves)
#define ITERS 4                    // chunks per block

typedef float f4 __attribute__((ext_vector_type(4)));  // native vec for builtins

__global__ __launch_bounds__(BLOCK, 4) void moe_kernel(
    const float* __restrict__ x,
    const float* __restrict__ W1,
    const float* __restrict__ b1,
    const float* __restrict__ W2,
    const float* __restrict__ b2,
    const int*   __restrict__ route,
    float*       __restrict__ out,
    int n)
{
    __shared__ f4 lds[(BLOCK / 64) * F4_PER_WAVE];  // 20 KB

    const int lane = threadIdx.x & 63;
    const int wave = threadIdx.x >> 6;
    f4* __restrict__ wlds = lds + wave * F4_PER_WAVE;

    const long long blkbase = (long long)blockIdx.x * (BLK_ROWS * ITERS);

    auto wave_rowbase = [&](int it) -> long long {
        return blkbase + (long long)it * BLK_ROWS + (long long)wave * WAVE_ROWS;
    };

    auto load_chunk = [&](int it, f4* bx, int2& br) {
        const long long rb = wave_rowbase(it);
        const f4* __restrict__ xv = (const f4*)(x + rb * D);
        #pragma unroll
        for (int j = 0; j < 5; ++j)
            bx[j] = xv[j * 64 + lane];
        br = ((const int2*)(route + rb))[lane];
    };

    auto process_chunk = [&](int it, const f4* bx, int2 br) {
        const long long rb = wave_rowbase(it);
        f4* __restrict__ ov = (f4*)(out + rb * D);

        // stage-in: regs -> LDS (lane-contiguous slots)
        #pragma unroll
        for (int j = 0; j < 5; ++j)
            wlds[j * 64 + lane] = bx[j];
        __builtin_amdgcn_wave_barrier();

        // gather this lane's 2 rows (stride 20 floats: conflict-free, 0 meas.)
        float xf[2 * D];
        #pragma unroll
        for (int j = 0; j < 5; ++j) {
            f4 t = wlds[lane * 5 + j];
            xf[4 * j + 0] = t.x; xf[4 * j + 1] = t.y;
            xf[4 * j + 2] = t.z; xf[4 * j + 3] = t.w;
        }

        const int rsel[2] = {br.x, br.y};
        float yf[2 * D];
        #pragma unroll
        for (int r = 0; r < 2; ++r) {
            #pragma unroll
            for (int j = 0; j < D; ++j) {
                float y0 = b1[j];
                float y1 = b2[j];
                #pragma unroll
                for (int k = 0; k < D; ++k) {
                    const float xk = xf[r * D + k];
                    y0 = fmaf(xk, W1[j * D + k], y0);
                    y1 = fmaf(xk, W2[j * D + k], y1);
                }
                yf[r * D + j] = rsel[r] ? y1 : y0;
            }
        }

        // scatter y -> LDS (same wave-ordered addresses; DS ops in-order)
        #pragma unroll
        for (int j = 0; j < 5; ++j) {
            f4 t;
            t.x = yf[4 * j + 0]; t.y = yf[4 * j + 1];
            t.z = yf[4 * j + 2]; t.w = yf[4 * j + 3];
            wlds[lane * 5 + j] = t;
        }
        __builtin_amdgcn_wave_barrier();

        // store-out: LDS -> global, coalesced, nontemporal (no reuse)
        #pragma unroll
        for (int j = 0; j < 5; ++j) {
            f4 t = wlds[j * 64 + lane];
            __builtin_nontemporal_store(t, &ov[j * 64 + lane]);
        }
        __builtin_amdgcn_wave_barrier();  // keep next iter's ds_writes behind
    };

    if (blkbase + (long long)ITERS * BLK_ROWS <= n) {
        // ---------- fast path: pipelined, register double-buffer ----------
        f4   buf[2][5];
        int2 brt[2];
        load_chunk(0, buf[0], brt[0]);
        #pragma unroll
        for (int it = 0; it < ITERS; ++it) {
            if (it + 1 < ITERS)
                load_chunk(it + 1, buf[(it + 1) & 1], brt[(it + 1) & 1]);
            process_chunk(it, buf[it & 1], brt[it & 1]);
        }
    } else {
        // ---------- tail path (not hit for N=2097152) ----------
        for (int it = 0; it < ITERS; ++it) {
            for (int r = 0; r < 2; ++r) {
                const long long row = wave_rowbase(it) + lane * 2 + r;
                if (row < n) {
                    const int sel = route[row];
                    for (int j = 0; j < D; ++j) {
                        float y0 = b1[j];
                        float y1 = b2[j];
                        for (int k = 0; k < D; ++k) {
                            const float xk = x[row * D + k];
                            y0 = fmaf(xk, W1[j * D + k], y0);
                            y1 = fmaf(xk, W2[j * D + k], y1);
                        }
                        out[row * D + j] = sel ? y1 : y0;
                    }
                }
            }
        }
    }
}

extern "C" void kernel_launch(void* const* d_in, const int* in_sizes, int n_in,
                              void* d_out, int out_size, void* d_ws, size_t ws_size,
                              hipStream_t stream) {
    const float* x     = (const float*)d_in[0];
    const float* W1    = (const float*)d_in[1];
    const float* b1    = (const float*)d_in[2];
    const float* W2    = (const float*)d_in[3];
    const float* b2    = (const float*)d_in[4];
    const int*   route = (const int*)d_in[5];
    float*       out   = (float*)d_out;

    const int n = in_sizes[5];  // N tokens (route length)
    const int rows_per_block = BLK_ROWS * ITERS;  // 2048
    const int blocks = (n + rows_per_block - 1) / rows_per_block;  // 1024

    moe_kernel<<<blocks, BLOCK, 0, stream>>>(x, W1, b1, W2, b2, route, out, n);
}